// Round 1
// baseline (2327.376 us; speedup 1.0000x reference)
//
#include <hip/hip_runtime.h>
#include <math.h>

#define N_RN 100000
#define N_ED 1200000
#define N_G  4096

__device__ __forceinline__ float lrelu(float x) { return x > 0.f ? x : 0.1f * x; }

// order-preserving float->uint encoding for atomicMax-based segment max
__device__ __forceinline__ unsigned enc_f(float f) {
    unsigned u = __float_as_uint(f);
    return (u & 0x80000000u) ? ~u : (u | 0x80000000u);
}
__device__ __forceinline__ float dec_f(unsigned u) {
    return (u & 0x80000000u) ? __uint_as_float(u ^ 0x80000000u) : __uint_as_float(~u);
}

// h[n][j] = sum_d r_node[n][d] * W_r[d][j]   (wave per node, lane = j)
__global__ void k_embed_h(const float* __restrict__ r_node,
                          const float* __restrict__ W_r,
                          float* __restrict__ h) {
    __shared__ float Wl[64 * 64];
    int tid = threadIdx.x;
    for (int i = tid; i < 4096; i += 256) Wl[i] = W_r[i];
    __syncthreads();
    int lane = tid & 63;
    int wid = blockIdx.x * 4 + (tid >> 6);
    int nw = gridDim.x * 4;
    for (int n = wid; n < N_RN; n += nw) {
        const float4* row = (const float4*)(r_node + (size_t)n * 64);
        float acc = 0.f;
#pragma unroll
        for (int d4 = 0; d4 < 16; ++d4) {
            float4 r = row[d4];
            int d = d4 * 4;
            acc += r.x * Wl[(d + 0) * 64 + lane];
            acc += r.y * Wl[(d + 1) * 64 + lane];
            acc += r.z * Wl[(d + 2) * 64 + lane];
            acc += r.w * Wl[(d + 3) * 64 + lane];
        }
        h[(size_t)n * 64 + lane] = acc;
    }
}

// el[l][k] = (r_edge[k] @ W_e) . a_e[l] = r_edge[k] . (W_e @ a_e[l])
__global__ void k_el(const float* __restrict__ r_edge,
                     const float* __restrict__ W_e,
                     const float* __restrict__ a_e,
                     float* __restrict__ el) {
    __shared__ float wa[4][16];
    int tid = threadIdx.x;
    if (tid < 64) {
        int l = tid >> 4, t = tid & 15;
        float acc = 0.f;
        for (int j = 0; j < 64; ++j) acc += W_e[t * 64 + j] * a_e[l * 64 + j];
        wa[l][t] = acc;
    }
    __syncthreads();
    int k = blockIdx.x * blockDim.x + tid;
    if (k >= N_ED) return;
    const float4* row = (const float4*)(r_edge + (size_t)k * 16);
    float4 r0 = row[0], r1 = row[1], r2 = row[2], r3 = row[3];
#pragma unroll
    for (int l = 0; l < 4; ++l) {
        float acc = r0.x * wa[l][0] + r0.y * wa[l][1] + r0.z * wa[l][2] + r0.w * wa[l][3]
                  + r1.x * wa[l][4] + r1.y * wa[l][5] + r1.z * wa[l][6] + r1.w * wa[l][7]
                  + r2.x * wa[l][8] + r2.y * wa[l][9] + r2.z * wa[l][10] + r2.w * wa[l][11]
                  + r3.x * wa[l][12] + r3.y * wa[l][13] + r3.z * wa[l][14] + r3.w * wa[l][15];
        el[(size_t)l * N_ED + k] = acc;
    }
}

// per-node scalars hs = h . a_s, hd = h . a_d  (wave per node, butterfly reduce)
__global__ void k_hshd(const float* __restrict__ h,
                       const float* __restrict__ a_s,
                       const float* __restrict__ a_d,
                       float* __restrict__ hs, float* __restrict__ hd) {
    int tid = threadIdx.x, lane = tid & 63;
    float asj = a_s[lane], adj = a_d[lane];
    int wid = blockIdx.x * 4 + (tid >> 6);
    int nw = gridDim.x * 4;
    for (int n = wid; n < N_RN; n += nw) {
        float v = h[(size_t)n * 64 + lane];
        float x = v * asj, y = v * adj;
#pragma unroll
        for (int off = 32; off; off >>= 1) {
            x += __shfl_xor(x, off, 64);
            y += __shfl_xor(y, off, 64);
        }
        if (lane == 0) { hs[n] = x; hd[n] = y; }
    }
}

// logits + segment max via atomicMax on encoded uint
__global__ void k_logit(const float* __restrict__ hs, const float* __restrict__ hd,
                        const float* __restrict__ el_l,
                        const int* __restrict__ src, const int* __restrict__ dst,
                        float* __restrict__ p, unsigned* __restrict__ menc) {
    int k = blockIdx.x * blockDim.x + threadIdx.x;
    if (k >= N_ED) return;
    int sk = src[k], dk = dst[k];
    float lg = lrelu(hs[sk] + hd[dk] + el_l[k]);
    p[k] = lg;
    atomicMax(menc + dk, enc_f(lg));
}

// p = exp(logit - m[dst]); segment sum via atomicAdd
__global__ void k_expsum(const int* __restrict__ dst,
                         float* __restrict__ p,
                         const unsigned* __restrict__ menc,
                         float* __restrict__ s) {
    int k = blockIdx.x * blockDim.x + threadIdx.x;
    if (k >= N_ED) return;
    int dk = dst[k];
    float m = dec_f(menc[dk]);
    float pv = __expf(p[k] - m);
    p[k] = pv;
    atomicAdd(s + dk, pv);
}

// msg pass: wave per edge, lane = feature. e recomputed from r_edge row x W_e (LDS).
__global__ void k_msg(const float* __restrict__ r_edge,
                      const float* __restrict__ W_e,
                      const float* __restrict__ h,
                      const int* __restrict__ src, const int* __restrict__ dst,
                      const float* __restrict__ p, const float* __restrict__ s,
                      float* __restrict__ agg) {
    __shared__ float We[16 * 64];
    int tid = threadIdx.x;
    for (int i = tid; i < 1024; i += 256) We[i] = W_e[i];
    __syncthreads();
    int lane = tid & 63;
    int wid = blockIdx.x * 4 + (tid >> 6);
    int nw = gridDim.x * 4;
    for (int k = wid; k < N_ED; k += nw) {
        int sk = src[k], dk = dst[k];
        float attn = p[k] / s[dk];
        float hsrc = h[(size_t)sk * 64 + lane];
        const float4* row = (const float4*)(r_edge + (size_t)k * 16);
        float4 r0 = row[0], r1 = row[1], r2 = row[2], r3 = row[3];
        float e = r0.x * We[0 * 64 + lane] + r0.y * We[1 * 64 + lane]
                + r0.z * We[2 * 64 + lane] + r0.w * We[3 * 64 + lane]
                + r1.x * We[4 * 64 + lane] + r1.y * We[5 * 64 + lane]
                + r1.z * We[6 * 64 + lane] + r1.w * We[7 * 64 + lane]
                + r2.x * We[8 * 64 + lane] + r2.y * We[9 * 64 + lane]
                + r2.z * We[10 * 64 + lane] + r2.w * We[11 * 64 + lane]
                + r3.x * We[12 * 64 + lane] + r3.y * We[13 * 64 + lane]
                + r3.z * We[14 * 64 + lane] + r3.w * We[15 * 64 + lane];
        atomicAdd(agg + (size_t)dk * 64 + lane, attn * (hsrc + e));
    }
}

// h = lrelu(h + agg @ Wm[l])  (wave per node; agg row staged through LDS for broadcast)
__global__ void k_update(float* __restrict__ h,
                         const float* __restrict__ agg,
                         const float* __restrict__ Wm_l) {
    __shared__ float Wl[64 * 64];
    __shared__ float arow[4][64];
    int tid = threadIdx.x;
    for (int i = tid; i < 4096; i += 256) Wl[i] = Wm_l[i];
    __syncthreads();
    int lane = tid & 63, w = tid >> 6;
    int wid = blockIdx.x * 4 + w;
    int nw = gridDim.x * 4;
    for (int n = wid; n < N_RN; n += nw) {
        float aj = agg[(size_t)n * 64 + lane];
        arow[w][lane] = aj;
        float acc = 0.f;
#pragma unroll
        for (int d4 = 0; d4 < 16; ++d4) {
            float4 a = *(const float4*)&arow[w][d4 * 4];
            int d = d4 * 4;
            acc += a.x * Wl[(d + 0) * 64 + lane];
            acc += a.y * Wl[(d + 1) * 64 + lane];
            acc += a.z * Wl[(d + 2) * 64 + lane];
            acc += a.w * Wl[(d + 3) * 64 + lane];
        }
        size_t idx = (size_t)n * 64 + lane;
        h[idx] = lrelu(h[idx] + acc);
    }
}

// block per graph (graph_id sorted -> contiguous ranges via binary search):
// pooled[g] = sum(h) + (sum gate) * hi_new[g];  hi_new = i_node*W_i + sum(gate*h)
// then 3-layer ReLU MLP + linear out, all in one 64-thread block.
__global__ void k_readout(const float* __restrict__ h,
                          const float* __restrict__ d_edge,
                          const int* __restrict__ graph_id,
                          const float* __restrict__ i_node,
                          const float* __restrict__ W_i,
                          const float* __restrict__ w_d,
                          const float* __restrict__ b_d,
                          const float* __restrict__ W_mlp,
                          const float* __restrict__ b_mlp,
                          const float* __restrict__ W_out,
                          const float* __restrict__ b_out,
                          float* __restrict__ out) {
    int g = blockIdx.x, j = threadIdx.x;
    int lo = 0, hi = N_RN;
    while (lo < hi) { int mid = (lo + hi) >> 1; if (graph_id[mid] < g) lo = mid + 1; else hi = mid; }
    int start = lo;
    hi = N_RN;
    while (lo < hi) { int mid = (lo + hi) >> 1; if (graph_id[mid] < g + 1) lo = mid + 1; else hi = mid; }
    int end = lo;

    float wd = w_d[0], bd = b_d[0];
    float acc0 = 0.f, acc1 = 0.f, sg = 0.f;
    for (int n = start; n < end; ++n) {
        float hv = h[(size_t)n * 64 + j];
        float de = d_edge[n];
        float gate = 1.f / (1.f + __expf(-(de * wd + bd)));
        acc0 += hv;
        acc1 += gate * hv;
        sg += gate;
    }
    float hij = i_node[g] * W_i[j] + acc1;
    float pooled = acc0 + sg * hij;

    __shared__ float xa[64], xb[64];
    xa[j] = pooled;
    __syncthreads();
#pragma unroll
    for (int layer = 0; layer < 3; ++layer) {
        const float* W = W_mlp + layer * 4096;
        float* srcb = (layer & 1) ? xb : xa;
        float* dstb = (layer & 1) ? xa : xb;
        float acc = b_mlp[layer * 64 + j];
        for (int d = 0; d < 64; ++d) acc += srcb[d] * W[d * 64 + j];
        acc = fmaxf(acc, 0.f);
        __syncthreads();
        dstb[j] = acc;
        __syncthreads();
    }
    float v = xb[j] * W_out[j];
#pragma unroll
    for (int off = 32; off; off >>= 1) v += __shfl_xor(v, off, 64);
    if (j == 0) out[g] = v + b_out[0];
}

extern "C" void kernel_launch(void* const* d_in, const int* in_sizes, int n_in,
                              void* d_out, int out_size, void* d_ws, size_t ws_size,
                              hipStream_t stream) {
    const float* r_node  = (const float*)d_in[0];
    const float* i_node  = (const float*)d_in[1];
    const float* r_edge  = (const float*)d_in[2];
    const float* d_edge  = (const float*)d_in[3];
    const int*   r2r_src = (const int*)d_in[4];
    const int*   r2r_dst = (const int*)d_in[5];
    const int*   graph_id= (const int*)d_in[6];
    const float* W_r     = (const float*)d_in[7];
    const float* W_i     = (const float*)d_in[8];
    const float* W_e     = (const float*)d_in[9];
    const float* Wm      = (const float*)d_in[10];
    const float* a_s     = (const float*)d_in[11];
    const float* a_d     = (const float*)d_in[12];
    const float* a_e     = (const float*)d_in[13];
    const float* w_d     = (const float*)d_in[14];
    const float* b_d     = (const float*)d_in[15];
    const float* W_mlp   = (const float*)d_in[16];
    const float* b_mlp   = (const float*)d_in[17];
    const float* W_out   = (const float*)d_in[18];
    const float* b_out   = (const float*)d_in[19];
    float* out = (float*)d_out;

    float* ws = (float*)d_ws;
    float*    h    = ws;                                 // N*64
    float*    agg  = h + (size_t)N_RN * 64;              // N*64
    unsigned* menc = (unsigned*)(agg + (size_t)N_RN * 64); // N
    float*    sbuf = (float*)(menc + N_RN);              // N
    float*    hs   = sbuf + N_RN;                        // N
    float*    hd   = hs + N_RN;                          // N
    float*    el   = hd + N_RN;                          // 4*E
    float*    p    = el + (size_t)4 * N_ED;              // E

    k_embed_h<<<1024, 256, 0, stream>>>(r_node, W_r, h);
    k_el<<<(N_ED + 255) / 256, 256, 0, stream>>>(r_edge, W_e, a_e, el);

    for (int l = 0; l < 4; ++l) {
        // zero agg (N*64) + menc (N) + sbuf (N) in one contiguous memset
        hipMemsetAsync(agg, 0, ((size_t)N_RN * 64 + 2 * (size_t)N_RN) * sizeof(float), stream);
        k_hshd<<<512, 256, 0, stream>>>(h, a_s + l * 64, a_d + l * 64, hs, hd);
        k_logit<<<(N_ED + 255) / 256, 256, 0, stream>>>(hs, hd, el + (size_t)l * N_ED,
                                                        r2r_src, r2r_dst, p, menc);
        k_expsum<<<(N_ED + 255) / 256, 256, 0, stream>>>(r2r_dst, p, menc, sbuf);
        k_msg<<<4096, 256, 0, stream>>>(r_edge, W_e, h, r2r_src, r2r_dst, p, sbuf, agg);
        k_update<<<1024, 256, 0, stream>>>(h, agg, Wm + l * 4096);
    }

    k_readout<<<N_G, 64, 0, stream>>>(h, d_edge, graph_id, i_node, W_i, w_d, b_d,
                                      W_mlp, b_mlp, W_out, b_out, out);
}

// Round 2
// 1935.427 us; speedup vs baseline: 1.2025x; 1.2025x over previous
//
#include <hip/hip_runtime.h>
#include <math.h>

#define N_RN 100000
#define N_ED 1200000
#define N_G  4096

__device__ __forceinline__ float lrelu(float x) { return x > 0.f ? x : 0.1f * x; }

__device__ __forceinline__ unsigned enc_f(float f) {
    unsigned u = __float_as_uint(f);
    return (u & 0x80000000u) ? ~u : (u | 0x80000000u);
}
__device__ __forceinline__ float dec_f(unsigned u) {
    return (u & 0x80000000u) ? __uint_as_float(u ^ 0x80000000u) : __uint_as_float(~u);
}

// h = r_node @ W_r  (wave per node, lane = out col; row staged via coalesced LDS)
// also fused: hs = h . a_s[0], hd = h . a_d[0]
__global__ void k_embed_h(const float* __restrict__ r_node,
                          const float* __restrict__ W_r,
                          const float* __restrict__ a_s0,
                          const float* __restrict__ a_d0,
                          float* __restrict__ h,
                          float* __restrict__ hs, float* __restrict__ hd) {
    __shared__ float Wl[64 * 64];
    __shared__ float arow[4][64];
    int tid = threadIdx.x;
    for (int i = tid; i < 4096; i += 256) Wl[i] = W_r[i];
    __syncthreads();
    int lane = tid & 63, w = tid >> 6;
    float asj = a_s0[lane], adj = a_d0[lane];
    int wid = blockIdx.x * 4 + w;
    int nw = gridDim.x * 4;
    for (int n = wid; n < N_RN; n += nw) {
        arow[w][lane] = r_node[(size_t)n * 64 + lane];  // coalesced 256B per wave
        float acc = 0.f;
#pragma unroll
        for (int d4 = 0; d4 < 16; ++d4) {
            float4 a = *(const float4*)&arow[w][d4 * 4];  // LDS broadcast
            int d = d4 * 4;
            acc += a.x * Wl[(d + 0) * 64 + lane];
            acc += a.y * Wl[(d + 1) * 64 + lane];
            acc += a.z * Wl[(d + 2) * 64 + lane];
            acc += a.w * Wl[(d + 3) * 64 + lane];
        }
        h[(size_t)n * 64 + lane] = acc;
        float x = acc * asj, y = acc * adj;
#pragma unroll
        for (int off = 32; off; off >>= 1) {
            x += __shfl_xor(x, off, 64);
            y += __shfl_xor(y, off, 64);
        }
        if (lane == 0) { hs[n] = x; hd[n] = y; }
    }
}

// el[l][k] = r_edge[k] . (W_e @ a_e[l])  (thread per edge, coalesced float4 row loads)
__global__ void k_el(const float* __restrict__ r_edge,
                     const float* __restrict__ W_e,
                     const float* __restrict__ a_e,
                     float* __restrict__ el) {
    __shared__ float wa[4][16];
    int tid = threadIdx.x;
    if (tid < 64) {
        int l = tid >> 4, t = tid & 15;
        float acc = 0.f;
        for (int j = 0; j < 64; ++j) acc += W_e[t * 64 + j] * a_e[l * 64 + j];
        wa[l][t] = acc;
    }
    __syncthreads();
    int k = blockIdx.x * blockDim.x + tid;
    if (k >= N_ED) return;
    const float4* row = (const float4*)(r_edge + (size_t)k * 16);
    float4 r0 = row[0], r1 = row[1], r2 = row[2], r3 = row[3];
#pragma unroll
    for (int l = 0; l < 4; ++l) {
        float acc = r0.x * wa[l][0] + r0.y * wa[l][1] + r0.z * wa[l][2] + r0.w * wa[l][3]
                  + r1.x * wa[l][4] + r1.y * wa[l][5] + r1.z * wa[l][6] + r1.w * wa[l][7]
                  + r2.x * wa[l][8] + r2.y * wa[l][9] + r2.z * wa[l][10] + r2.w * wa[l][11]
                  + r3.x * wa[l][12] + r3.y * wa[l][13] + r3.z * wa[l][14] + r3.w * wa[l][15];
        el[(size_t)l * N_ED + k] = acc;
    }
}

// logits + segment max via atomicMax on encoded uint
__global__ void k_logit(const float* __restrict__ hs, const float* __restrict__ hd,
                        const float* __restrict__ el_l,
                        const int* __restrict__ src, const int* __restrict__ dst,
                        float* __restrict__ p, unsigned* __restrict__ menc) {
    int k = blockIdx.x * blockDim.x + threadIdx.x;
    if (k >= N_ED) return;
    int sk = src[k], dk = dst[k];
    float lg = lrelu(hs[sk] + hd[dk] + el_l[k]);
    p[k] = lg;
    atomicMax(menc + dk, enc_f(lg));
}

// p = exp(logit - m[dst]); segment sum via atomicAdd
__global__ void k_expsum(const int* __restrict__ dst,
                         float* __restrict__ p,
                         const unsigned* __restrict__ menc,
                         float* __restrict__ s) {
    int k = blockIdx.x * blockDim.x + threadIdx.x;
    if (k >= N_ED) return;
    int dk = dst[k];
    float m = dec_f(menc[dk]);
    float pv = __expf(p[k] - m);
    p[k] = pv;
    atomicAdd(s + dk, pv);
}

// msg pass: wave per edge, lane = feature. edge row loaded coalesced, broadcast via shfl;
// W_e column held in registers (16 per lane).
__global__ void k_msg(const float* __restrict__ r_edge,
                      const float* __restrict__ W_e,
                      const float* __restrict__ h,
                      const int* __restrict__ src, const int* __restrict__ dst,
                      const float* __restrict__ p, const float* __restrict__ s,
                      float* __restrict__ agg) {
    int tid = threadIdx.x;
    int lane = tid & 63;
    float wecol[16];
#pragma unroll
    for (int t = 0; t < 16; ++t) wecol[t] = W_e[t * 64 + lane];  // coalesced
    int wid = blockIdx.x * 4 + (tid >> 6);
    int nw = gridDim.x * 4;
    for (int k = wid; k < N_ED; k += nw) {
        int sk = src[k], dk = dst[k];
        float attn = p[k] / s[dk];
        float hsrc = h[(size_t)sk * 64 + lane];
        float ev = r_edge[(size_t)k * 16 + (lane & 15)];  // one 64B line per wave
        float e = 0.f;
#pragma unroll
        for (int t = 0; t < 16; ++t) e += __shfl(ev, t, 64) * wecol[t];
        atomicAdd(agg + (size_t)dk * 64 + lane, attn * (hsrc + e));
    }
}

// h = lrelu(h + agg @ Wm[l]); fused hs/hd for next layer
__global__ void k_update(float* __restrict__ h,
                         const float* __restrict__ agg,
                         const float* __restrict__ Wm_l,
                         const float* __restrict__ a_s_n,
                         const float* __restrict__ a_d_n,
                         float* __restrict__ hs, float* __restrict__ hd) {
    __shared__ float Wl[64 * 64];
    __shared__ float arow[4][64];
    int tid = threadIdx.x;
    for (int i = tid; i < 4096; i += 256) Wl[i] = Wm_l[i];
    __syncthreads();
    int lane = tid & 63, w = tid >> 6;
    float asj = a_s_n[lane], adj = a_d_n[lane];
    int wid = blockIdx.x * 4 + w;
    int nw = gridDim.x * 4;
    for (int n = wid; n < N_RN; n += nw) {
        arow[w][lane] = agg[(size_t)n * 64 + lane];
        float acc = 0.f;
#pragma unroll
        for (int d4 = 0; d4 < 16; ++d4) {
            float4 a = *(const float4*)&arow[w][d4 * 4];
            int d = d4 * 4;
            acc += a.x * Wl[(d + 0) * 64 + lane];
            acc += a.y * Wl[(d + 1) * 64 + lane];
            acc += a.z * Wl[(d + 2) * 64 + lane];
            acc += a.w * Wl[(d + 3) * 64 + lane];
        }
        size_t idx = (size_t)n * 64 + lane;
        float hv = lrelu(h[idx] + acc);
        h[idx] = hv;
        float x = hv * asj, y = hv * adj;
#pragma unroll
        for (int off = 32; off; off >>= 1) {
            x += __shfl_xor(x, off, 64);
            y += __shfl_xor(y, off, 64);
        }
        if (lane == 0) { hs[n] = x; hd[n] = y; }
    }
}

// block per graph readout (graph_id sorted -> contiguous ranges via binary search)
__global__ void k_readout(const float* __restrict__ h,
                          const float* __restrict__ d_edge,
                          const int* __restrict__ graph_id,
                          const float* __restrict__ i_node,
                          const float* __restrict__ W_i,
                          const float* __restrict__ w_d,
                          const float* __restrict__ b_d,
                          const float* __restrict__ W_mlp,
                          const float* __restrict__ b_mlp,
                          const float* __restrict__ W_out,
                          const float* __restrict__ b_out,
                          float* __restrict__ out) {
    int g = blockIdx.x, j = threadIdx.x;
    int lo = 0, hi = N_RN;
    while (lo < hi) { int mid = (lo + hi) >> 1; if (graph_id[mid] < g) lo = mid + 1; else hi = mid; }
    int start = lo;
    hi = N_RN;
    while (lo < hi) { int mid = (lo + hi) >> 1; if (graph_id[mid] < g + 1) lo = mid + 1; else hi = mid; }
    int end = lo;

    float wd = w_d[0], bd = b_d[0];
    float acc0 = 0.f, acc1 = 0.f, sg = 0.f;
    for (int n = start; n < end; ++n) {
        float hv = h[(size_t)n * 64 + j];
        float de = d_edge[n];
        float gate = 1.f / (1.f + __expf(-(de * wd + bd)));
        acc0 += hv;
        acc1 += gate * hv;
        sg += gate;
    }
    float hij = i_node[g] * W_i[j] + acc1;
    float pooled = acc0 + sg * hij;

    __shared__ float xa[64], xb[64];
    xa[j] = pooled;
    __syncthreads();
#pragma unroll
    for (int layer = 0; layer < 3; ++layer) {
        const float* W = W_mlp + layer * 4096;
        float* srcb = (layer & 1) ? xb : xa;
        float* dstb = (layer & 1) ? xa : xb;
        float acc = b_mlp[layer * 64 + j];
        for (int d = 0; d < 64; ++d) acc += srcb[d] * W[d * 64 + j];
        acc = fmaxf(acc, 0.f);
        __syncthreads();
        dstb[j] = acc;
        __syncthreads();
    }
    float v = xb[j] * W_out[j];
#pragma unroll
    for (int off = 32; off; off >>= 1) v += __shfl_xor(v, off, 64);
    if (j == 0) out[g] = v + b_out[0];
}

extern "C" void kernel_launch(void* const* d_in, const int* in_sizes, int n_in,
                              void* d_out, int out_size, void* d_ws, size_t ws_size,
                              hipStream_t stream) {
    const float* r_node  = (const float*)d_in[0];
    const float* i_node  = (const float*)d_in[1];
    const float* r_edge  = (const float*)d_in[2];
    const float* d_edge  = (const float*)d_in[3];
    const int*   r2r_src = (const int*)d_in[4];
    const int*   r2r_dst = (const int*)d_in[5];
    const int*   graph_id= (const int*)d_in[6];
    const float* W_r     = (const float*)d_in[7];
    const float* W_i     = (const float*)d_in[8];
    const float* W_e     = (const float*)d_in[9];
    const float* Wm      = (const float*)d_in[10];
    const float* a_s     = (const float*)d_in[11];
    const float* a_d     = (const float*)d_in[12];
    const float* a_e     = (const float*)d_in[13];
    const float* w_d     = (const float*)d_in[14];
    const float* b_d     = (const float*)d_in[15];
    const float* W_mlp   = (const float*)d_in[16];
    const float* b_mlp   = (const float*)d_in[17];
    const float* W_out   = (const float*)d_in[18];
    const float* b_out   = (const float*)d_in[19];
    float* out = (float*)d_out;

    float* ws = (float*)d_ws;
    float*    h    = ws;                                   // N*64
    float*    agg  = h + (size_t)N_RN * 64;                // N*64
    unsigned* menc = (unsigned*)(agg + (size_t)N_RN * 64); // N
    float*    sbuf = (float*)(menc + N_RN);                // N
    float*    hs   = sbuf + N_RN;                          // N
    float*    hd   = hs + N_RN;                            // N
    float*    el   = hd + N_RN;                            // 4*E
    float*    p    = el + (size_t)4 * N_ED;                // E

    k_embed_h<<<2048, 256, 0, stream>>>(r_node, W_r, a_s, a_d, h, hs, hd);
    k_el<<<(N_ED + 255) / 256, 256, 0, stream>>>(r_edge, W_e, a_e, el);

    for (int l = 0; l < 4; ++l) {
        hipMemsetAsync(agg, 0, ((size_t)N_RN * 64 + 2 * (size_t)N_RN) * sizeof(float), stream);
        k_logit<<<(N_ED + 255) / 256, 256, 0, stream>>>(hs, hd, el + (size_t)l * N_ED,
                                                        r2r_src, r2r_dst, p, menc);
        k_expsum<<<(N_ED + 255) / 256, 256, 0, stream>>>(r2r_dst, p, menc, sbuf);
        k_msg<<<4096, 256, 0, stream>>>(r_edge, W_e, h, r2r_src, r2r_dst, p, sbuf, agg);
        int ln = (l + 1) & 3;
        k_update<<<2048, 256, 0, stream>>>(h, agg, Wm + l * 4096,
                                           a_s + ln * 64, a_d + ln * 64, hs, hd);
    }

    k_readout<<<N_G, 64, 0, stream>>>(h, d_edge, graph_id, i_node, W_i, w_d, b_d,
                                      W_mlp, b_mlp, W_out, b_out, out);
}